// Round 1
// 703.164 us; speedup vs baseline: 1.3276x; 1.3276x over previous
//
#include <hip/hip_runtime.h>
#include <hip/hip_bf16.h>

// GlobalGuideLayer: B=16, N=8192, C=256, h=4, d=64, N1=64, proj=skip_proj=64.
// Dtypes (established rounds 0-4): ALL fp32, inputs AND output, exactly per
// the reference. (Threshold = 2% of max|ref|; the "bf16" label text is a
// template artifact. Rounds 2/4 failed only because output was written bf16.)
#define B_SZ  16
#define N_TOK 8192
#define C_DIM 256
#define NH    4

// ---------------------------------------------------------------------------
// Zero kp+vp region of ws: 524288 floats = 2 MB. grid 512 x 256.
// ---------------------------------------------------------------------------
__global__ __launch_bounds__(256) void zero_kernel(float4* __restrict__ p) {
    p[(size_t)blockIdx.x * 256 + threadIdx.x] = make_float4(0.f, 0.f, 0.f, 0.f);
}

// ---------------------------------------------------------------------------
// kp[b,c,k] = sum_n skip[b,n,c]*EF2[n,k], via atomicAdd of 512-token chunk
// partials. v2 (this round): same grid of 256 blocks (atomic count unchanged
// at 4.2M) but 1024 threads/block: thread (c = tid&255, kq = tid>>8) owns 16
// of the 64 k's. The 4 kq wave-groups re-load the same skip values (L1-
// absorbed within the CU) -> no cross-wave reduction needed. Token loop
// unrolled x8 for 8 loads in flight. Prev version: 1 wave/SIMD, no unroll,
// VALUBusy 5%, 555 us. Floor is max(27 us VALU, 20 us HBM).
// grid (16, 16), block 1024.
// ---------------------------------------------------------------------------
__global__ __launch_bounds__(1024) void kp_atomic_kernel(
    const float* __restrict__ skip,
    const float* __restrict__ ef2,
    float* __restrict__ kp)
{
    __shared__ float ef2_lds[128][64];     // 32 KB window of EF2
    const int b = blockIdx.y, s = blockIdx.x;
    const int tid = threadIdx.x;
    const int c  = tid & 255;              // channel (lane-consecutive -> coalesced)
    const int kq = tid >> 8;               // k-quarter: k in [kq*16, kq*16+16)

    float acc[16];
#pragma unroll
    for (int k = 0; k < 16; ++k) acc[k] = 0.f;

    // 512-token chunk = 4 windows of 128 tokens
    for (int w = 0; w < 4; ++w) {
        const int n0 = s * 512 + w * 128;
        __syncthreads();                   // guard previous window's readers
        const float4* src = reinterpret_cast<const float4*>(ef2 + (size_t)n0 * 64);
        float4* dst_l = reinterpret_cast<float4*>(&ef2_lds[0][0]);
#pragma unroll
        for (int i = 0; i < 2; ++i)        // 2048 float4 = 128 rows x 64
            dst_l[i * 1024 + tid] = src[i * 1024 + tid];
        __syncthreads();

        const float* sp = skip + ((size_t)b * N_TOK + n0) * C_DIM + c;
        for (int nn = 0; nn < 128; nn += 8) {
            float v[8];
#pragma unroll
            for (int j = 0; j < 8; ++j)    // 8 independent coalesced loads
                v[j] = sp[(size_t)(nn + j) * C_DIM];
#pragma unroll
            for (int j = 0; j < 8; ++j) {
                const float4* row =
                    reinterpret_cast<const float4*>(&ef2_lds[nn + j][kq * 16]);
#pragma unroll
                for (int k4 = 0; k4 < 4; ++k4) {   // LDS broadcast reads
                    float4 e = row[k4];
                    acc[k4*4+0] += v[j] * e.x;
                    acc[k4*4+1] += v[j] * e.y;
                    acc[k4*4+2] += v[j] * e.z;
                    acc[k4*4+3] += v[j] * e.w;
                }
            }
        }
    }
    float* dst = kp + ((size_t)b * C_DIM + c) * 64 + kq * 16;
#pragma unroll
    for (int k = 0; k < 16; ++k) atomicAdd(dst + k, acc[k]);
}

// ---------------------------------------------------------------------------
// vp[b,c,m] = sum_{n1<64} gf[b,n1,c]*EF1[n1,m]. grid 16, block 256.
// ---------------------------------------------------------------------------
__global__ __launch_bounds__(256) void vp_kernel(
    const float* __restrict__ gf,
    const float* __restrict__ ef1,
    float* __restrict__ vp)
{
    __shared__ float ef1_lds[64][64];      // 16 KB
    const int b = blockIdx.x, tid = threadIdx.x;
    const float4* src = reinterpret_cast<const float4*>(ef1);
    float4* dst_l = reinterpret_cast<float4*>(&ef1_lds[0][0]);
#pragma unroll
    for (int i = 0; i < 4; ++i)            // 1024 float4 = 64 x 64
        dst_l[i * 256 + tid] = src[i * 256 + tid];
    __syncthreads();
    float acc[64];
#pragma unroll
    for (int k = 0; k < 64; ++k) acc[k] = 0.f;
    const float* gp = gf + (size_t)b * 64 * C_DIM + tid;
    for (int n = 0; n < 64; ++n) {
        float v = gp[(size_t)n * C_DIM];
        const float4* row = reinterpret_cast<const float4*>(ef1_lds[n]);
#pragma unroll
        for (int k4 = 0; k4 < 16; ++k4) {
            float4 e = row[k4];
            acc[k4*4+0] += v * e.x;
            acc[k4*4+1] += v * e.y;
            acc[k4*4+2] += v * e.z;
            acc[k4*4+3] += v * e.w;
        }
    }
    float* dst = vp + ((size_t)b * C_DIM + tid) * 64;
#pragma unroll
    for (int k4 = 0; k4 < 16; ++k4)
        reinterpret_cast<float4*>(dst)[k4] =
            make_float4(acc[k4*4+0], acc[k4*4+1], acc[k4*4+2], acc[k4*4+3]);
}

// ---------------------------------------------------------------------------
// attn: per (b,h,n): softmax(q.kp * temp) . vp
// y[b*2097152 + m*32768 + h*8192 + n]  (fp32). grid (32, NH, B), block 256.
// ---------------------------------------------------------------------------
__global__ __launch_bounds__(256) void attn_kernel(
    const float* __restrict__ outq,
    const float* __restrict__ kp,
    const float* __restrict__ vp,
    const float* __restrict__ temp,
    float* __restrict__ y)
{
    __shared__ float kp_lds[64][64];   // [d][k]
    __shared__ float vp_lds[64][64];   // [k][m]
    const int b = blockIdx.z, h = blockIdx.y, t = blockIdx.x;
    const int tid = threadIdx.x;

    const float* kps = kp + ((size_t)b * C_DIM + h * 64) * 64;
    const float* vps = vp + ((size_t)b * C_DIM + h * 64) * 64;
#pragma unroll
    for (int i = 0; i < 16; ++i) {
        int idx = i * 256 + tid;
        kp_lds[idx >> 6][idx & 63] = kps[idx];
        vp_lds[idx >> 6][idx & 63] = vps[idx];
    }
    __syncthreads();

    const int n = t * 256 + tid;
    const float4* q4 = reinterpret_cast<const float4*>(
        outq + ((size_t)b * N_TOK + n) * C_DIM + h * 64);

    float attn[64];
#pragma unroll
    for (int k = 0; k < 64; ++k) attn[k] = 0.f;

    for (int c4 = 0; c4 < 16; ++c4) {
        float4 u = q4[c4];
        float qv[4] = {u.x, u.y, u.z, u.w};
#pragma unroll
        for (int j = 0; j < 4; ++j) {
            const float qd = qv[j];
            const float4* row = reinterpret_cast<const float4*>(kp_lds[c4 * 4 + j]);
#pragma unroll
            for (int k4 = 0; k4 < 16; ++k4) {
                float4 e = row[k4];
                attn[k4*4+0] += qd * e.x;
                attn[k4*4+1] += qd * e.y;
                attn[k4*4+2] += qd * e.z;
                attn[k4*4+3] += qd * e.w;
            }
        }
    }

    const float ts = temp[h];
    float mx = -3.0e38f;
#pragma unroll
    for (int k = 0; k < 64; ++k) { attn[k] *= ts; mx = fmaxf(mx, attn[k]); }
    float sum = 0.f;
#pragma unroll
    for (int k = 0; k < 64; ++k) { float e = __expf(attn[k] - mx); attn[k] = e; sum += e; }
    const float inv = 1.f / sum;
#pragma unroll
    for (int k = 0; k < 64; ++k) attn[k] *= inv;

    float* yb = y + (size_t)b * (N_TOK * C_DIM) + (size_t)h * N_TOK + n;
    const float4* vp4 = reinterpret_cast<const float4*>(&vp_lds[0][0]);
    for (int m4 = 0; m4 < 16; ++m4) {
        float4 r = make_float4(0.f, 0.f, 0.f, 0.f);
#pragma unroll
        for (int k = 0; k < 64; ++k) {
            float4 e = vp4[k * 16 + m4];
            r.x += attn[k] * e.x;
            r.y += attn[k] * e.y;
            r.z += attn[k] * e.z;
            r.w += attn[k] * e.w;
        }
        yb[(size_t)(m4*4+0) * (NH * N_TOK)] = r.x;
        yb[(size_t)(m4*4+1) * (NH * N_TOK)] = r.y;
        yb[(size_t)(m4*4+2) * (NH * N_TOK)] = r.z;
        yb[(size_t)(m4*4+3) * (NH * N_TOK)] = r.w;
    }
}

// ---------------------------------------------------------------------------
// Zero-workspace fallback: block (h, b, tq) recomputes kp/vp in LDS, then
// attention for its quarter of tokens. grid (NH, B, 4), block 256. LDS 64 KB.
// ---------------------------------------------------------------------------
__global__ __launch_bounds__(256) void fused_kernel(
    const float* __restrict__ skip, const float* __restrict__ outq,
    const float* __restrict__ gf,   const float* __restrict__ ef1,
    const float* __restrict__ ef2,  const float* __restrict__ temp,
    float* __restrict__ y)
{
    __shared__ float kp_l[64][64];
    __shared__ float vp_l[64][64];
    __shared__ float stA[64][64];
    __shared__ float stB[64][64];
    const int h = blockIdx.x, b = blockIdx.y, tq = blockIdx.z;
    const int tid = threadIdx.x;
    const int d = tid & 63, q4i = tid >> 6;

    float acc[16];
#pragma unroll
    for (int j = 0; j < 16; ++j) acc[j] = 0.f;

    for (int n0 = 0; n0 < N_TOK; n0 += 64) {
        __syncthreads();
#pragma unroll
        for (int i = 0; i < 16; ++i) {
            int idx = i * 256 + tid; int nn = idx >> 6, dd = idx & 63;
            stA[nn][dd] = skip[((size_t)b * N_TOK + n0 + nn) * C_DIM + h * 64 + dd];
            stB[nn][dd] = ef2[(size_t)(n0 + nn) * 64 + dd];
        }
        __syncthreads();
        for (int nn = 0; nn < 64; ++nn) {
            float v = stA[nn][d];
            const float4* row = reinterpret_cast<const float4*>(&stB[nn][q4i * 16]);
#pragma unroll
            for (int j4 = 0; j4 < 4; ++j4) {
                float4 e = row[j4];
                acc[j4*4+0] += v * e.x; acc[j4*4+1] += v * e.y;
                acc[j4*4+2] += v * e.z; acc[j4*4+3] += v * e.w;
            }
        }
    }
    __syncthreads();
#pragma unroll
    for (int j = 0; j < 16; ++j) kp_l[d][q4i * 16 + j] = acc[j];

#pragma unroll
    for (int j = 0; j < 16; ++j) acc[j] = 0.f;
#pragma unroll
    for (int i = 0; i < 16; ++i) {
        int idx = i * 256 + tid; int nn = idx >> 6, dd = idx & 63;
        stA[nn][dd] = gf[((size_t)b * 64 + nn) * C_DIM + h * 64 + dd];
        stB[nn][dd] = ef1[(size_t)nn * 64 + dd];
    }
    __syncthreads();
    for (int nn = 0; nn < 64; ++nn) {
        float v = stA[nn][d];
        const float4* row = reinterpret_cast<const float4*>(&stB[nn][q4i * 16]);
#pragma unroll
        for (int j4 = 0; j4 < 4; ++j4) {
            float4 e = row[j4];
            acc[j4*4+0] += v * e.x; acc[j4*4+1] += v * e.y;
            acc[j4*4+2] += v * e.z; acc[j4*4+3] += v * e.w;
        }
    }
#pragma unroll
    for (int j = 0; j < 16; ++j) vp_l[d][q4i * 16 + j] = acc[j];
    __syncthreads();

    const float ts = temp[h];
    const float4* vp4 = reinterpret_cast<const float4*>(&vp_l[0][0]);
    for (int t = 0; t < 8; ++t) {
        const int n = tq * 2048 + t * 256 + tid;
        const float4* q4 = reinterpret_cast<const float4*>(
            outq + ((size_t)b * N_TOK + n) * C_DIM + h * 64);
        float attn[64];
#pragma unroll
        for (int k = 0; k < 64; ++k) attn[k] = 0.f;
        for (int c4 = 0; c4 < 16; ++c4) {
            float4 u = q4[c4];
            float qv[4] = {u.x, u.y, u.z, u.w};
#pragma unroll
            for (int j = 0; j < 4; ++j) {
                const float qd = qv[j];
                const float4* row = reinterpret_cast<const float4*>(kp_l[c4 * 4 + j]);
#pragma unroll
                for (int k4 = 0; k4 < 16; ++k4) {
                    float4 e = row[k4];
                    attn[k4*4+0] += qd * e.x;
                    attn[k4*4+1] += qd * e.y;
                    attn[k4*4+2] += qd * e.z;
                    attn[k4*4+3] += qd * e.w;
                }
            }
        }
        float mx = -3.0e38f;
#pragma unroll
        for (int k = 0; k < 64; ++k) { attn[k] *= ts; mx = fmaxf(mx, attn[k]); }
        float sum = 0.f;
#pragma unroll
        for (int k = 0; k < 64; ++k) { float e = __expf(attn[k] - mx); attn[k] = e; sum += e; }
        const float inv = 1.f / sum;
#pragma unroll
        for (int k = 0; k < 64; ++k) attn[k] *= inv;

        float* yb = y + (size_t)b * (N_TOK * C_DIM) + (size_t)h * N_TOK + n;
        for (int m4 = 0; m4 < 16; ++m4) {
            float4 r = make_float4(0.f, 0.f, 0.f, 0.f);
#pragma unroll
            for (int k = 0; k < 64; ++k) {
                float4 e = vp4[k * 16 + m4];
                r.x += attn[k] * e.x;
                r.y += attn[k] * e.y;
                r.z += attn[k] * e.z;
                r.w += attn[k] * e.w;
            }
            yb[(size_t)(m4*4+0) * (NH * N_TOK)] = r.x;
            yb[(size_t)(m4*4+1) * (NH * N_TOK)] = r.y;
            yb[(size_t)(m4*4+2) * (NH * N_TOK)] = r.z;
            yb[(size_t)(m4*4+3) * (NH * N_TOK)] = r.w;
        }
    }
}

extern "C" void kernel_launch(void* const* d_in, const int* in_sizes, int n_in,
                              void* d_out, int out_size, void* d_ws, size_t ws_size,
                              hipStream_t stream) {
    const float* skip = (const float*)d_in[0];
    const float* outq = (const float*)d_in[1];
    const float* gf   = (const float*)d_in[2];
    const float* ef1  = (const float*)d_in[3];
    const float* ef2  = (const float*)d_in[4];
    const float* temp = (const float*)d_in[5];
    float* y = (float*)d_out;

    if (ws_size >= (size_t)524288 * 4) {
        // fast path: exactly 2 MB of ws (kp 1 MB + vp 1 MB)
        float* kp = (float*)d_ws;
        float* vp = kp + 262144;
        zero_kernel<<<512, 256, 0, stream>>>((float4*)d_ws);
        kp_atomic_kernel<<<dim3(16, B_SZ), 1024, 0, stream>>>(skip, ef2, kp);
        vp_kernel<<<B_SZ, 256, 0, stream>>>(gf, ef1, vp);
        attn_kernel<<<dim3(32, NH, B_SZ), 256, 0, stream>>>(outq, kp, vp, temp, y);
    } else {
        // zero-workspace fallback
        fused_kernel<<<dim3(NH, B_SZ, 4), 256, 0, stream>>>(skip, outq, gf, ef1, ef2, temp, y);
    }
}